// Round 12
// baseline (24.565 us; speedup 1.0000x reference)
//
#include <hip/hip_runtime.h>
#include <math.h>
#include <string.h>

#define NJ 24
#define NV 6890
#define NB 128

// Ancestor chains (closest ancestor first), -1 padded. Max depth 8.
__constant__ int d_anc[NJ][8] = {
  {-1,-1,-1,-1,-1,-1,-1,-1},
  { 0,-1,-1,-1,-1,-1,-1,-1},
  { 0,-1,-1,-1,-1,-1,-1,-1},
  { 0,-1,-1,-1,-1,-1,-1,-1},
  { 1, 0,-1,-1,-1,-1,-1,-1},
  { 2, 0,-1,-1,-1,-1,-1,-1},
  { 3, 0,-1,-1,-1,-1,-1,-1},
  { 4, 1, 0,-1,-1,-1,-1,-1},
  { 5, 2, 0,-1,-1,-1,-1,-1},
  { 6, 3, 0,-1,-1,-1,-1,-1},
  { 7, 4, 1, 0,-1,-1,-1,-1},
  { 8, 5, 2, 0,-1,-1,-1,-1},
  { 9, 6, 3, 0,-1,-1,-1,-1},
  { 9, 6, 3, 0,-1,-1,-1,-1},
  { 9, 6, 3, 0,-1,-1,-1,-1},
  {12, 9, 6, 3, 0,-1,-1,-1},
  {13, 9, 6, 3, 0,-1,-1,-1},
  {14, 9, 6, 3, 0,-1,-1,-1},
  {16,13, 9, 6, 3, 0,-1,-1},
  {17,14, 9, 6, 3, 0,-1,-1},
  {18,16,13, 9, 6, 3, 0,-1},
  {19,17,14, 9, 6, 3, 0,-1},
  {20,18,16,13, 9, 6, 3, 0},
  {21,19,17,14, 9, 6, 3, 0}
};
__constant__ int d_par[NJ] = {-1,0,0,0,1,2,3,4,5,6,7,8,9,9,9,12,13,14,16,17,18,19,20,21};

typedef __attribute__((ext_vector_type(8))) short bf16x8;
typedef __attribute__((ext_vector_type(4))) float f32x4;

__device__ __forceinline__ short f2bf(float f) {
    unsigned int u;
    memcpy(&u, &f, 4);
    u += 0x7fffu + ((u >> 16) & 1u);   // round-to-nearest-even
    return (short)(u >> 16);
}

#define TLSTRIDE 20   // floats per scratch row: 80 B, 16B-aligned

// FUSED kernel (R11) + chain/W-prefetch overlap: group-0's W loads (8 float4
// per lane, +32 VGPR) are ISSUED BEFORE the chain barriers, so HBM latency
// for the first 32 B/lane of W hides under the chain's compute + pose/J
// latency instead of the whole block idling at __syncthreads.
__global__ __launch_bounds__(256) void lbs_fused(const float* __restrict__ V,
                                                 const float* __restrict__ J,
                                                 const float* __restrict__ pose,
                                                 const float* __restrict__ W,
                                                 float* __restrict__ out) {
    const int b    = blockIdx.y;
    const int tid  = threadIdx.x;
    const int wave = tid >> 6;
    const int lane = tid & 63;
    const int vwave = blockIdx.x * 1024 + wave * 256;   // 256 verts per wave
    const int n16 = lane & 15;   // A: vertex slot | B: out-elem n | C: col
    const int g   = lane >> 4;   // k-group (8 joints per group)
    const bool wactive = (vwave < NV);

    __shared__ float A_lds[NJ][12];
    __shared__ float Gc_lds[NJ * 12];
    __shared__ float tl[4 * 64 * TLSTRIDE];

    // ---- Prefetch: group-0 W tiles into registers (in flight during chain).
    float4 pfl[4], pfh[4];
    #pragma unroll
    for (int t = 0; t < 4; t++) {
        pfl[t] = make_float4(0.f, 0.f, 0.f, 0.f);
        pfh[t] = make_float4(0.f, 0.f, 0.f, 0.f);
        if (wactive && g < 3) {
            const int v  = vwave + t * 16 + n16;
            const int vc = v < NV ? v : NV - 1;
            const float4* wp = (const float4*)(W + ((size_t)b * NV + vc) * 24 + g * 8);
            pfl[t] = wp[0];
            pfh[t] = wp[1];
        }
    }

    // ---- Phase 0: chain (all threads reach both barriers) ----
    if (tid < NJ) {
        const int i = tid;
        const float* p = pose + ((size_t)b * NJ + i) * 3;
        float rx = p[0], ry = p[1], rz = p[2];
        float ex = rx + 1e-8f, ey = ry + 1e-8f, ez = rz + 1e-8f;
        float theta = sqrtf(ex * ex + ey * ey + ez * ez);
        float inv = 1.0f / theta;
        float hx = rx * inv, hy = ry * inv, hz = rz * inv;
        float c = cosf(theta * (float)M_PI);
        float s = sinf(theta);
        float oc = 1.0f - c;
        const float* jp = J + ((size_t)b * NJ + i) * 3;
        int par = d_par[i];
        float tx, ty, tz;
        if (par < 0) {
            tx = jp[0]; ty = jp[1]; tz = jp[2];
        } else {
            const float* jq = J + ((size_t)b * NJ + par) * 3;
            tx = jp[0] - jq[0]; ty = jp[1] - jq[1]; tz = jp[2] - jq[2];
        }
        A_lds[i][0]  = c + oc * hx * hx;
        A_lds[i][1]  = oc * hx * hy - s * hz;
        A_lds[i][2]  = oc * hx * hz + s * hy;
        A_lds[i][3]  = tx;
        A_lds[i][4]  = oc * hy * hx + s * hz;
        A_lds[i][5]  = c + oc * hy * hy;
        A_lds[i][6]  = oc * hy * hz - s * hx;
        A_lds[i][7]  = ty;
        A_lds[i][8]  = oc * hz * hx - s * hy;
        A_lds[i][9]  = oc * hz * hy + s * hx;
        A_lds[i][10] = c + oc * hz * hz;
        A_lds[i][11] = tz;
    }
    __syncthreads();

    if (tid < NJ) {
        const int i = tid;
        float M[12];
        #pragma unroll
        for (int j = 0; j < 12; j++) M[j] = A_lds[i][j];

        for (int k = 0; k < 8; k++) {
            int p = d_anc[i][k];
            if (p < 0) break;
            float P[12];
            #pragma unroll
            for (int j = 0; j < 12; j++) P[j] = A_lds[p][j];
            float N[12];
            #pragma unroll
            for (int r = 0; r < 3; r++) {
                float p0 = P[r*4+0], p1 = P[r*4+1], p2 = P[r*4+2], p3 = P[r*4+3];
                N[r*4+0] = p0 * M[0] + p1 * M[4] + p2 * M[8];
                N[r*4+1] = p0 * M[1] + p1 * M[5] + p2 * M[9];
                N[r*4+2] = p0 * M[2] + p1 * M[6] + p2 * M[10];
                N[r*4+3] = p0 * M[3] + p1 * M[7] + p2 * M[11] + p3;
            }
            #pragma unroll
            for (int j = 0; j < 12; j++) M[j] = N[j];
        }

        const float* jp = J + ((size_t)b * NJ + i) * 3;
        float jx = jp[0], jy = jp[1], jz = jp[2];
        #pragma unroll
        for (int r = 0; r < 3; r++) {
            float g0 = M[r*4+0], g1 = M[r*4+1], g2 = M[r*4+2], g3 = M[r*4+3];
            float corr = g0 * jx + g1 * jy + g2 * jz;
            Gc_lds[i*12 + r*4+0] = g0;
            Gc_lds[i*12 + r*4+1] = g1;
            Gc_lds[i*12 + r*4+2] = g2;
            Gc_lds[i*12 + r*4+3] = g3 - corr;
        }
    }
    __syncthreads();

    // ---- Phase 1: MFMA skinning ----
    if (!wactive) return;

    float* mytl = &tl[wave * 64 * TLSTRIDE];

    // B fragment: B[k][n] = Gc[joint k][elem n], k = 8g + j; zero-padded.
    bf16x8 bfrag;
    #pragma unroll
    for (int j = 0; j < 8; j++) {
        const int k = 8 * g + j;
        const float gval = (k < NJ && n16 < 12) ? Gc_lds[k * 12 + n16] : 0.0f;
        bfrag[j] = f2bf(gval);
    }

    auto do_tile = [&](int t, float4 l4, float4 h4) {
        bf16x8 afrag;
        afrag[0] = f2bf(l4.x); afrag[1] = f2bf(l4.y);
        afrag[2] = f2bf(l4.z); afrag[3] = f2bf(l4.w);
        afrag[4] = f2bf(h4.x); afrag[5] = f2bf(h4.y);
        afrag[6] = f2bf(h4.z); afrag[7] = f2bf(h4.w);
        f32x4 acc = {0.f, 0.f, 0.f, 0.f};
        acc = __builtin_amdgcn_mfma_f32_16x16x32_bf16(afrag, bfrag, acc, 0, 0, 0);
        #pragma unroll
        for (int r = 0; r < 4; r++) {
            const int lv = t * 16 + 4 * g + r;
            mytl[lv * TLSTRIDE + n16] = acc[r];
        }
    };

    auto do_epilogue = [&](int gbase) {
        __builtin_amdgcn_wave_barrier();
        const int gv  = gbase + lane;
        const int gvc = gv < NV ? gv : NV - 1;
        const float* row = &mytl[lane * TLSTRIDE];
        f32x4 t0 = *(const f32x4*)(row + 0);
        f32x4 t1 = *(const f32x4*)(row + 4);
        f32x4 t2 = *(const f32x4*)(row + 8);
        const float* vp = V + ((size_t)b * NV + gvc) * 3;
        const float vx = vp[0], vy = vp[1], vz = vp[2];
        if (gv < NV) {
            float* op = out + ((size_t)b * NV + gv) * 3;
            op[0] = t0[0] * vx + t0[1] * vy + t0[2] * vz + t0[3];
            op[1] = t1[0] * vx + t1[1] * vy + t1[2] * vz + t1[3];
            op[2] = t2[0] * vx + t2[1] * vy + t2[2] * vz + t2[3];
        }
        __builtin_amdgcn_wave_barrier();
    };

    // Group 0: consume prefetched registers.
    #pragma unroll
    for (int t = 0; t < 4; t++) do_tile(t, pfl[t], pfh[t]);
    do_epilogue(vwave);

    // Groups 1..3: load in-loop.
    #pragma unroll 1
    for (int grp = 1; grp < 4; grp++) {
        const int gbase = vwave + grp * 64;
        #pragma unroll
        for (int t = 0; t < 4; t++) {
            float4 l4 = make_float4(0.f, 0.f, 0.f, 0.f);
            float4 h4 = make_float4(0.f, 0.f, 0.f, 0.f);
            if (g < 3) {
                const int v  = gbase + t * 16 + n16;
                const int vc = v < NV ? v : NV - 1;
                const float4* wp =
                    (const float4*)(W + ((size_t)b * NV + vc) * 24 + g * 8);
                l4 = wp[0];
                h4 = wp[1];
            }
            do_tile(t, l4, h4);
        }
        do_epilogue(gbase);
    }
}

extern "C" void kernel_launch(void* const* d_in, const int* in_sizes, int n_in,
                              void* d_out, int out_size, void* d_ws, size_t ws_size,
                              hipStream_t stream) {
    const float* V    = (const float*)d_in[0];
    const float* J    = (const float*)d_in[1];
    const float* pose = (const float*)d_in[2];
    const float* W    = (const float*)d_in[3];
    float* out = (float*)d_out;

    dim3 grid((NV + 1023) / 1024, NB);
    lbs_fused<<<grid, 256, 0, stream>>>(V, J, pose, W, out);
}